// Round 16
// baseline (750.440 us; speedup 1.0000x reference)
//
#include <hip/hip_runtime.h>
#include <hip/hip_fp16.h>

#define B_Q 1024
#define C_P 65536
#define D_DIM 1024
#define CAND_CAP 512
#define REF_CAP 128
#define CELL_CAP 16
#define T0_CAPTURE 0.090f
#define BM 128
#define BN 256
#define BK 64

typedef float f32x4 __attribute__((ext_vector_type(4)));

// Monotonic order-preserving keys for fp16 bit patterns.
__device__ __forceinline__ unsigned h2key(unsigned h) {
  return (h & 0x8000u) ? (0xFFFFu ^ h) : (h | 0x8000u);
}
__device__ __forceinline__ unsigned short key2h(unsigned k) {
  return (k & 0x8000u) ? (unsigned short)(k & 0x7FFFu)
                       : (unsigned short)(~k & 0xFFFFu);
}

// Async global->LDS, 16B per lane. LDS dest = wave-uniform base + lane*16.
__device__ __forceinline__ void gload16(const unsigned char* g,
                                        unsigned char* l) {
  __builtin_amdgcn_global_load_lds(
      (const __attribute__((address_space(1))) unsigned int*)g,
      (__attribute__((address_space(3))) unsigned int*)l, 16, 0, 0);
}

#define FENCE asm volatile("" ::: "memory")
#define BAR                         \
  do {                              \
    FENCE;                          \
    __builtin_amdgcn_s_barrier();   \
    FENCE;                          \
  } while (0)
#define VMC(n) asm volatile("s_waitcnt vmcnt(" #n ")" ::: "memory")
#define SP1 __builtin_amdgcn_s_setprio(1)
#define SP0 __builtin_amdgcn_s_setprio(0)

// ---------------- K1: row L2-normalize -> fp8 e4m3 copy + inverse norms -----
__global__ __launch_bounds__(256) void k_rownorm(
    const float* __restrict__ src, unsigned char* __restrict__ dst,
    float* __restrict__ inv_out, int nrows) {
  const int lane = threadIdx.x & 63;
  const int wave = threadIdx.x >> 6;
  const int row = blockIdx.x * 4 + wave;
  if (row >= nrows) return;
  const float4* r4 = (const float4*)(src + (size_t)row * D_DIM);
  float4 v[4];
  float ss = 0.f;
#pragma unroll
  for (int j = 0; j < 4; ++j) {
    v[j] = r4[lane + j * 64];
    ss += v[j].x * v[j].x + v[j].y * v[j].y + v[j].z * v[j].z + v[j].w * v[j].w;
  }
#pragma unroll
  for (int off = 32; off; off >>= 1) ss += __shfl_xor(ss, off);
  const float inv = 1.0f / fmaxf(sqrtf(ss), 1e-8f);
  if (lane == 0) inv_out[row] = inv;
  unsigned* d1 = (unsigned*)(dst + (size_t)row * D_DIM);
#pragma unroll
  for (int j = 0; j < 4; ++j) {
    unsigned r = __builtin_amdgcn_cvt_pk_fp8_f32(v[j].x * inv, v[j].y * inv, 0, 0);
    r = __builtin_amdgcn_cvt_pk_fp8_f32(v[j].z * inv, v[j].w * inv, r, 1);
    d1[lane + j * 64] = r;
  }
}

// ---------------- K2: fp8 GEMM 128x256, 2 phases/K-tile, 3 blocks/CU --------
// 8 waves (2M x 4N), per-wave 64x64 out (acc 64 regs -> ~130 unified, no
// spill). LDS 2 x (8KB A + 16KB B) = 48KB -> 3 blocks/CU (24 waves, 6/SIMD):
// cross-block overlap hides LDS reads + barriers under MFMA (r15 at 2
// blocks/CU plateaued at 46% of the fp8 MFMA ceiling).
// Staging calendar (>=1-phase write-after-read separation, counted guards):
//   P1(t): reads A(c), B-lo(c); stage B(t+1)->buf c^1 (its B reads issued
//          P2(t-1), barrier between)
//   P2(t): reads B-hi(c); stage A(t+2)->buf c (A reads issued P1(t));
//          guard vmcnt(1): forces tile t+1 landed, newest A prefetch flies.
#define STG_A(buf, R0, t) \
  gload16(pAg + (size_t)(R0)*D_DIM + (t)*BK, &As[buf][(R0)*64] + wave * 1024)
#define STG_B(buf, R0, t) \
  gload16(pBg + (size_t)(R0)*D_DIM + (t)*BK, &Bs[buf][(R0)*64] + wave * 1024)

#define RD_A(buf)                                                           \
  _Pragma("unroll") for (int m = 0; m < 4; ++m) {                           \
    _Pragma("unroll") for (int kk = 0; kk < 2; ++kk) {                      \
      const int r_ = wm * 64 + m * 16 + rr;                                 \
      const int s8 = kk * 4 + klane;                                        \
      const int ph = (((s8 >> 1) ^ xr) * 16) + (s8 & 1) * 8;                \
      af[m * 2 + kk] = *(const long*)&As[buf][r_ * 64 + ph];                \
    }                                                                       \
  }

#define RD_B(dst, buf, nbase)                                               \
  _Pragma("unroll") for (int n = 0; n < 2; ++n) {                           \
    _Pragma("unroll") for (int kk = 0; kk < 2; ++kk) {                      \
      const int r_ = wn * 64 + ((nbase) + n) * 16 + rr;                     \
      const int s8 = kk * 4 + klane;                                        \
      const int ph = (((s8 >> 1) ^ xr) * 16) + (s8 & 1) * 8;                \
      dst[n * 2 + kk] = *(const long*)&Bs[buf][r_ * 64 + ph];               \
    }                                                                       \
  }

#define MM(nbase, bsrc)                                                     \
  _Pragma("unroll") for (int m = 0; m < 4; ++m) {                           \
    _Pragma("unroll") for (int n = 0; n < 2; ++n) {                         \
      _Pragma("unroll") for (int kk = 0; kk < 2; ++kk) {                    \
        acc[m][(nbase) + n] =                                               \
            __builtin_amdgcn_mfma_f32_16x16x32_fp8_fp8(                     \
                af[m * 2 + kk], bsrc[n * 2 + kk],                           \
                acc[m][(nbase) + n], 0, 0, 0);                              \
      }                                                                     \
    }                                                                       \
  }

__global__ __launch_bounds__(512, 6) void k_gemm(
    const unsigned char* __restrict__ qn8,
    const unsigned char* __restrict__ pn8, unsigned* __restrict__ gcl,
    unsigned* __restrict__ counts) {
  __shared__ __align__(16) unsigned char As[2][BM * 64];
  __shared__ __align__(16) unsigned char Bs[2][BN * 64];
  const int tid = threadIdx.x;
  const int lane = tid & 63;
  const int wave = tid >> 6;
  const int wm = wave >> 2;  // 0..1
  const int wn = wave & 3;   // 0..3
  const int bCol = blockIdx.x * BN;
  const int bRow = blockIdx.y * BM;
  const int rr = lane & 15;
  const int klane = lane >> 4;
  const int xr = (rr & 3) ^ ((rr >> 2) & 3);

  // Staging source: thread tid covers row (tid>>2), 16-B chunk (tid&3) with
  // the inverse swizzle pre-applied to the global column.
  const int srow = tid >> 2;  // 0..127
  const int xrs = (srow & 3) ^ ((srow >> 2) & 3);
  const int scol = ((tid & 3) ^ xrs) * 16;
  const unsigned char* pAg = qn8 + (size_t)(bRow + srow) * D_DIM + scol;
  const unsigned char* pBg = pn8 + (size_t)(bCol + srow) * D_DIM + scol;

  f32x4 acc[4][4];
#pragma unroll
  for (int m = 0; m < 4; ++m)
#pragma unroll
    for (int n = 0; n < 4; ++n) acc[m][n] = (f32x4){0.f, 0.f, 0.f, 0.f};
  long af[8], blo[4], bhi[4];

  // Prologue: tiles 0 (buf0) and 1 (buf1); force tile0's 3 landed, tile1 flies.
  STG_A(0, 0, 0); STG_B(0, 0, 0); STG_B(0, 128, 0);
  STG_A(1, 0, 1); STG_B(1, 0, 1); STG_B(1, 128, 1);
  VMC(3);
  BAR;

  for (int t = 0; t < 16; ++t) {
    const int c = t & 1;
    // P1: A + B-lo of tile t; stage B(t+1) into buf c^1
    RD_A(c);
    RD_B(blo, c, 0);
    if (t >= 1 && t <= 14) { STG_B(c ^ 1, 0, t + 1); STG_B(c ^ 1, 128, t + 1); }
    BAR; SP1; MM(0, blo); SP0; BAR;
    // P2: B-hi of tile t; stage A(t+2) into buf c; tile-boundary guard
    RD_B(bhi, c, 2);
    if (t <= 13) STG_A(c, 0, t + 2);
    BAR; SP1; MM(2, bhi); SP0;
    if (t < 14) { VMC(1); } else { VMC(0); }  // force tile t+1 landed
    BAR;
  }

  // ---- Fused epilogue: static-threshold candidate extraction ----
  // acc[m][n][r]: row = wm*64+m*16+klane*4+r, col = wn*64+n*16+rr.
  __syncthreads();
  unsigned* rcnt = (unsigned*)&As[0][0];  // 128 per-row slot counters
  if (tid < 128) rcnt[tid] = 0u;
  __syncthreads();
  const int blk = bCol >> 8;
#pragma unroll
  for (int m = 0; m < 4; ++m)
#pragma unroll
    for (int r = 0; r < 4; ++r) {
      const int row = wm * 64 + m * 16 + klane * 4 + r;
#pragma unroll
      for (int n = 0; n < 4; ++n) {
        const float v = acc[m][n][r];
        if (v >= T0_CAPTURE) {
          const unsigned p = atomicAdd(&rcnt[row], 1u);
          if (p < CELL_CAP) {
            const unsigned col = (unsigned)(bCol + wn * 64 + n * 16 + rr);
            const unsigned hb = (unsigned)__half_as_ushort(__float2half(v));
            gcl[((size_t)(bRow + row) * 256 + blk) * CELL_CAP + p] =
                (h2key(hb) << 16) | col;
          }
        }
      }
    }
  __syncthreads();
  if (tid < 128) {
    unsigned c = rcnt[tid];
    counts[(size_t)(bRow + tid) * 256 + blk] = c > CELL_CAP ? CELL_CAP : c;
  }
}

// ------- K3: gather, fp16 pre-rank, f64 refine survivors, top-16, out -------
__global__ __launch_bounds__(256) void k_final(
    const float* __restrict__ qc, const float* __restrict__ pat,
    const float* __restrict__ comp, const float* __restrict__ invq,
    const float* __restrict__ invp, const unsigned* __restrict__ gcl,
    const unsigned* __restrict__ counts, float* __restrict__ out) {
  const int b = blockIdx.x;
  const int tid = threadIdx.x;
  const int lane = tid & 63;
  const int wave = tid >> 6;
  __shared__ float qs[1024];
  __shared__ unsigned skey[CAND_CAP];
  __shared__ int ci[CAND_CAP];
  __shared__ double sv[REF_CAP];
  __shared__ int rci[REF_CAP];
  __shared__ int s_cnt, s_rcnt;
  __shared__ unsigned s_tkey;
  __shared__ int topi[16];
  __shared__ double tops[16];
  __shared__ float wgt[16];
  if (tid == 0) { s_cnt = 0; s_rcnt = 0; }
  ((float4*)qs)[tid] = ((const float4*)(qc + (size_t)b * D_DIM))[tid];
  __syncthreads();
  {
    unsigned c = counts[(size_t)b * 256 + tid];
    if (c > CELL_CAP) c = CELL_CAP;
    const size_t base = ((size_t)b * 256 + tid) * CELL_CAP;
    for (unsigned p = 0; p < c; ++p) {
      const unsigned e = gcl[base + p];
      int pos = atomicAdd(&s_cnt, 1);
      if (pos < CAND_CAP) {
        skey[pos] = e >> 16;
        ci[pos] = (int)(e & 0xFFFFu);
      }
    }
  }
  __syncthreads();
  int cnt = s_cnt;
  if (cnt > CAND_CAP) cnt = CAND_CAP;
  // Wave 0: 16th-largest fp16 key -> refine threshold. Margin 8e-3 covers
  // ~5.3 sigma of fp8-dot noise (sigma ~1.5e-3) + fp16 quantization.
  if (wave == 0) {
    unsigned wk[8];
#pragma unroll
    for (int j = 0; j < 8; ++j) {
      const int s = lane + j * 64;
      wk[j] = (s < cnt) ? skey[s] : 0u;
    }
    unsigned sk = 0;
    for (int it = 0; it < 16; ++it) {
      unsigned loc = 0;
#pragma unroll
      for (int j = 0; j < 8; ++j) loc = max(loc, wk[j]);
      unsigned mx = loc;
#pragma unroll
      for (int off = 32; off; off >>= 1)
        mx = max(mx, (unsigned)__shfl_xor((int)mx, off));
      unsigned long long msk = __ballot(loc == mx && mx != 0u);
      int winner = __ffsll(msk) - 1;
      if (lane == winner) {
#pragma unroll
        for (int j = 0; j < 8; ++j)
          if (wk[j] == mx) { wk[j] = 0u; break; }
      }
      if (mx != 0u) sk = mx;
    }
    if (lane == 0) {
      const float sf = __half2float(__ushort_as_half(key2h(sk)));
      const unsigned short tb = __half_as_ushort(__float2half(sf - 8e-3f));
      s_tkey = h2key((unsigned)tb);
    }
  }
  __syncthreads();
  const unsigned tkey = s_tkey;
  for (int i = tid; i < cnt; i += 256) {
    if (skey[i] >= tkey) {
      int pos = atomicAdd(&s_rcnt, 1);
      if (pos < REF_CAP) rci[pos] = ci[i];
    }
  }
  __syncthreads();
  int rcnt = s_rcnt;
  if (rcnt > REF_CAP) rcnt = REF_CAP;
  const double sq = (double)invq[b];
  for (int i = wave; i < rcnt; i += 4) {
    const float4* p4 = (const float4*)(pat + (size_t)rci[i] * D_DIM);
    const float4* q4 = (const float4*)qs;
    double acc = 0.0;
#pragma unroll
    for (int j = 0; j < 4; ++j) {
      float4 p = p4[lane + j * 64];
      float4 q = q4[lane + j * 64];
      acc += (double)p.x * q.x + (double)p.y * q.y + (double)p.z * q.z +
             (double)p.w * q.w;
    }
#pragma unroll
    for (int off = 32; off; off >>= 1) acc += __shfl_xor(acc, off);
    if (lane == 0) sv[i] = acc * sq * (double)invp[rci[i]];
  }
  __syncthreads();
  if (wave == 0) {
    for (int k = 0; k < 16; ++k) {
      double bs = -1e300;
      int bi = 0x7FFFFFFF, bslot = -1;
      for (int s = lane; s < rcnt; s += 64) {
        double d = sv[s];
        int id = rci[s];
        if (d > bs || (d == bs && id < bi)) { bs = d; bi = id; bslot = s; }
      }
#pragma unroll
      for (int off = 32; off; off >>= 1) {
        double ds = __shfl_xor(bs, off);
        int di = __shfl_xor(bi, off);
        int dsl = __shfl_xor(bslot, off);
        if (ds > bs || (ds == bs && di < bi)) { bs = ds; bi = di; bslot = dsl; }
      }
      if (lane == 0) {
        if (bi == 0x7FFFFFFF) bi = 0;  // safety: never index OOB
        topi[k] = bi;
        tops[k] = bs;
        if (bslot >= 0) sv[bslot] = -1e301;
      }
    }
    if (lane < 16) {
      float ts = (float)tops[lane];
      wgt[lane] = ts * (1.0f + comp[topi[lane]]);
    }
  }
  __syncthreads();
  if (tid == 0) {  // softmax over 16
    float m = wgt[0];
    for (int k = 1; k < 16; ++k) m = fmaxf(m, wgt[k]);
    float e[16];
    float ssum = 0.f;
    for (int k = 0; k < 16; ++k) {
      e[k] = expf(wgt[k] - m);
      ssum += e[k];
    }
    for (int k = 0; k < 16; ++k) wgt[k] = e[k] / ssum;
  }
  __syncthreads();
  float4 a4 = {0.f, 0.f, 0.f, 0.f};
  for (int k = 0; k < 16; ++k) {
    float4 pv = ((const float4*)(pat + (size_t)topi[k] * D_DIM))[tid];
    const float w = wgt[k];
    a4.x += w * pv.x;
    a4.y += w * pv.y;
    a4.z += w * pv.z;
    a4.w += w * pv.w;
  }
  ((float4*)(out + (size_t)b * D_DIM))[tid] = a4;
  if (tid == 0) out[1048576 + b] = (float)tops[0];
  if (tid < 16) {
    out[1048576 + 1024 + b * 16 + tid] = (float)topi[tid];
    out[1048576 + 1024 + 16384 + b * 16 + tid] = (float)tops[tid];
  }
}

extern "C" void kernel_launch(void* const* d_in, const int* in_sizes, int n_in,
                              void* d_out, int out_size, void* d_ws,
                              size_t ws_size, hipStream_t stream) {
  const float* qc = (const float*)d_in[0];
  const float* pat = (const float*)d_in[1];
  const float* comp = (const float*)d_in[2];
  char* ws = (char*)d_ws;
  unsigned char* pn8 = (unsigned char*)(ws + 0);              // 64 MB
  unsigned char* qn8 = (unsigned char*)(ws + 67108864);       // 1 MB
  unsigned* gcl = (unsigned*)(ws + 69206016);                 // 16 MB
  unsigned* counts = (unsigned*)(ws + 85983232);              // 1 MB
  float* invp = (float*)(ws + 88080384);                      // 256 KB
  float* invq = (float*)(ws + 88342528);                      // 4 KB
  float* out = (float*)d_out;

  k_rownorm<<<C_P / 4, 256, 0, stream>>>(pat, pn8, invp, C_P);
  k_rownorm<<<B_Q / 4, 256, 0, stream>>>(qc, qn8, invq, B_Q);
  dim3 g2(C_P / BN, B_Q / BM);
  k_gemm<<<g2, 512, 0, stream>>>(qn8, pn8, gcl, counts);
  k_final<<<B_Q, 256, 0, stream>>>(qc, pat, comp, invq, invp, gcl, counts, out);
}

// Round 17
// 212.924 us; speedup vs baseline: 3.5245x; 3.5245x over previous
//
#include <hip/hip_runtime.h>
#include <hip/hip_fp16.h>

#define B_Q 1024
#define C_P 65536
#define D_DIM 1024
#define CAND_CAP 512
#define REF_CAP 128
#define CELL_CAP 16
#define T0_CAPTURE 0.090f
#define QSCALE 512.0f
#define INV_QSCALE2 (1.0f / (512.0f * 512.0f))
#define BM 256
#define BN 256
#define BK 64

typedef int i32x4 __attribute__((ext_vector_type(4)));

// Monotonic order-preserving keys for fp16 bit patterns.
__device__ __forceinline__ unsigned h2key(unsigned h) {
  return (h & 0x8000u) ? (0xFFFFu ^ h) : (h | 0x8000u);
}
__device__ __forceinline__ unsigned short key2h(unsigned k) {
  return (k & 0x8000u) ? (unsigned short)(k & 0x7FFFu)
                       : (unsigned short)(~k & 0xFFFFu);
}

// Async global->LDS, 16B per lane. LDS dest = wave-uniform base + lane*16.
__device__ __forceinline__ void gload16(const unsigned char* g,
                                        unsigned char* l) {
  __builtin_amdgcn_global_load_lds(
      (const __attribute__((address_space(1))) unsigned int*)g,
      (__attribute__((address_space(3))) unsigned int*)l, 16, 0, 0);
}

#define FENCE asm volatile("" ::: "memory")
#define BAR                         \
  do {                              \
    FENCE;                          \
    __builtin_amdgcn_s_barrier();   \
    FENCE;                          \
  } while (0)
#define VMC(n) asm volatile("s_waitcnt vmcnt(" #n ")" ::: "memory")
#define SP1 __builtin_amdgcn_s_setprio(1)
#define SP0 __builtin_amdgcn_s_setprio(0)

// -------- K1: row L2-normalize -> int8 copy (scale 512) + inverse norms -----
// Normalized entries ~N(0,1/32); *512 -> N(0,16); clamp +-127 fires w.p.
// ~1e-10 per element. Dot-error sigma ~7.9e-4 (< fp8's 1.5e-3).
__global__ __launch_bounds__(256) void k_rownorm(
    const float* __restrict__ src, unsigned char* __restrict__ dst,
    float* __restrict__ inv_out, int nrows) {
  const int lane = threadIdx.x & 63;
  const int wave = threadIdx.x >> 6;
  const int row = blockIdx.x * 4 + wave;
  if (row >= nrows) return;
  const float4* r4 = (const float4*)(src + (size_t)row * D_DIM);
  float4 v[4];
  float ss = 0.f;
#pragma unroll
  for (int j = 0; j < 4; ++j) {
    v[j] = r4[lane + j * 64];
    ss += v[j].x * v[j].x + v[j].y * v[j].y + v[j].z * v[j].z + v[j].w * v[j].w;
  }
#pragma unroll
  for (int off = 32; off; off >>= 1) ss += __shfl_xor(ss, off);
  const float inv = 1.0f / fmaxf(sqrtf(ss), 1e-8f);
  if (lane == 0) inv_out[row] = inv;
  unsigned* d1 = (unsigned*)(dst + (size_t)row * D_DIM);
#pragma unroll
  for (int j = 0; j < 4; ++j) {
    const float s = inv * QSCALE;
    int q0 = (int)rintf(v[j].x * s);
    int q1 = (int)rintf(v[j].y * s);
    int q2 = (int)rintf(v[j].z * s);
    int q3 = (int)rintf(v[j].w * s);
    q0 = q0 < -127 ? -127 : (q0 > 127 ? 127 : q0);
    q1 = q1 < -127 ? -127 : (q1 > 127 ? 127 : q1);
    q2 = q2 < -127 ? -127 : (q2 > 127 ? 127 : q2);
    q3 = q3 < -127 ? -127 : (q3 > 127 ? 127 : q3);
    d1[lane + j * 64] = (unsigned)(q0 & 0xFF) | ((unsigned)(q1 & 0xFF) << 8) |
                        ((unsigned)(q2 & 0xFF) << 16) |
                        ((unsigned)(q3 & 0xFF) << 24);
  }
}

// ---------------- K2: i8 GEMM 256x256 (mfma_i32_16x16x64_i8) ----------------
// r9/r15-proven structure: 8 waves (2M x 4N), per-wave 128x64 out, LDS
// 2 x (16KB A + 16KB B) = 64KB, 4 phases/K-tile, stage t+2, vmcnt(4) guard.
// i8 K=64 MFMA halves instruction count vs fp8 K=32 at 2x rate (m16);
// operands are clean 4-VGPR i32x4 (NOT mfma_scale's spilling v8i32).
// Frag read: ONE ds_read_b128 at 16B chunk klane^xr(row), xr=(r&3)^((r>>2)&3)
// (involution; staging source pre-applies it; ~2-way banking = free).
#define STG_A(buf, R0, t) \
  gload16(pAg + (size_t)(R0)*D_DIM + (t)*BK, &As[buf][(R0)*64] + wave * 1024)
#define STG_B(buf, R0, t) \
  gload16(pBg + (size_t)(R0)*D_DIM + (t)*BK, &Bs[buf][(R0)*64] + wave * 1024)

#define RD_A(buf, mbase)                                                    \
  _Pragma("unroll") for (int m = 0; m < 4; ++m) {                           \
    const int r_ = wm * 128 + ((mbase) + m) * 16 + rr;                      \
    af[m] = *(const i32x4*)&As[buf][r_ * 64 + ((klane ^ xr) * 16)];         \
  }

#define RD_B(dst, buf, nbase)                                               \
  _Pragma("unroll") for (int n = 0; n < 2; ++n) {                           \
    const int r_ = wn * 64 + ((nbase) + n) * 16 + rr;                       \
    dst[n] = *(const i32x4*)&Bs[buf][r_ * 64 + ((klane ^ xr) * 16)];        \
  }

#define MM(mbase, nbase, bsrc)                                              \
  _Pragma("unroll") for (int m = 0; m < 4; ++m) {                           \
    _Pragma("unroll") for (int n = 0; n < 2; ++n) {                         \
      acc[(mbase) + m][(nbase) + n] = __builtin_amdgcn_mfma_i32_16x16x64_i8( \
          af[m], bsrc[n], acc[(mbase) + m][(nbase) + n], 0, 0, 0);          \
    }                                                                       \
  }

__global__ __launch_bounds__(512, 2) void k_gemm(
    const unsigned char* __restrict__ qn8,
    const unsigned char* __restrict__ pn8, unsigned* __restrict__ gcl,
    unsigned* __restrict__ counts) {
  __shared__ __align__(16) unsigned char As[2][BM * 64];
  __shared__ __align__(16) unsigned char Bs[2][BN * 64];
  const int tid = threadIdx.x;
  const int lane = tid & 63;
  const int wave = tid >> 6;
  const int wm = wave >> 2;  // 0..1
  const int wn = wave & 3;   // 0..3
  const int bCol = blockIdx.x * BN;
  const int bRow = blockIdx.y * BM;
  const int rr = lane & 15;
  const int klane = lane >> 4;
  const int xr = (rr & 3) ^ ((rr >> 2) & 3);

  // Staging source: thread tid covers row (tid>>2), 16-B chunk (tid&3) with
  // the inverse swizzle pre-applied to the global column.
  const int srow = tid >> 2;  // 0..127
  const int xrs = (srow & 3) ^ ((srow >> 2) & 3);
  const int scol = ((tid & 3) ^ xrs) * 16;
  const unsigned char* pAg = qn8 + (size_t)(bRow + srow) * D_DIM + scol;
  const unsigned char* pBg = pn8 + (size_t)(bCol + srow) * D_DIM + scol;

  i32x4 acc[8][4];
#pragma unroll
  for (int m = 0; m < 8; ++m)
#pragma unroll
    for (int n = 0; n < 4; ++n) acc[m][n] = (i32x4){0, 0, 0, 0};
  i32x4 af[4], blo[2], bhi[2];

  // Prologue: tiles 0 (buf0) and 1 (buf1); force tile0 landed, tile1 flies.
  STG_A(0, 0, 0); STG_A(0, 128, 0); STG_B(0, 0, 0); STG_B(0, 128, 0);
  STG_A(1, 0, 1); STG_A(1, 128, 1); STG_B(1, 0, 1); STG_B(1, 128, 1);
  VMC(4);
  BAR;

  for (int t = 0; t < 16; ++t) {
    const int c = t & 1;
    const bool st = (t < 14);
    // Q0
    RD_A(c, 0);
    RD_B(blo, c, 0);
    BAR; SP1; MM(0, 0, blo); SP0; BAR;
    // Q1
    RD_B(bhi, c, 2);
    BAR; SP1; MM(0, 2, bhi); SP0; BAR;
    // Q2 (buf c's B free after Q1)
    RD_A(c, 4);
    if (st) STG_B(c, 0, t + 2);
    BAR; SP1; MM(4, 0, blo); SP0; BAR;
    // Q3 (buf c's A free after Q2) + tile-boundary guard
    if (st) { STG_B(c, 128, t + 2); STG_A(c, 0, t + 2); STG_A(c, 128, t + 2); }
    BAR; SP1; MM(4, 2, bhi); SP0;
    if (st) { VMC(4); } else { VMC(0); }  // force tile t+1 landed
    BAR;
  }

  // ---- Fused epilogue: static-threshold candidate extraction ----
  // acc[m][n][r]: row = wm*128+m*16+klane*4+r, col = wn*64+n*16+rr.
  __syncthreads();
  unsigned* rcnt = (unsigned*)&As[0][0];  // 256 per-row slot counters
  if (tid < 256) rcnt[tid] = 0u;
  __syncthreads();
  const int blk = bCol >> 8;
#pragma unroll
  for (int m = 0; m < 8; ++m)
#pragma unroll
    for (int r = 0; r < 4; ++r) {
      const int row = wm * 128 + m * 16 + klane * 4 + r;
#pragma unroll
      for (int n = 0; n < 4; ++n) {
        const float v = (float)acc[m][n][r] * INV_QSCALE2;
        if (v >= T0_CAPTURE) {
          const unsigned p = atomicAdd(&rcnt[row], 1u);
          if (p < CELL_CAP) {
            const unsigned col = (unsigned)(bCol + wn * 64 + n * 16 + rr);
            const unsigned hb = (unsigned)__half_as_ushort(__float2half(v));
            gcl[((size_t)(bRow + row) * 256 + blk) * CELL_CAP + p] =
                (h2key(hb) << 16) | col;
          }
        }
      }
    }
  __syncthreads();
  if (tid < 256) {
    unsigned c = rcnt[tid];
    counts[(size_t)(bRow + tid) * 256 + blk] = c > CELL_CAP ? CELL_CAP : c;
  }
}

// ------- K3: gather, fp16 pre-rank, f64 refine survivors, top-16, out -------
__global__ __launch_bounds__(256) void k_final(
    const float* __restrict__ qc, const float* __restrict__ pat,
    const float* __restrict__ comp, const float* __restrict__ invq,
    const float* __restrict__ invp, const unsigned* __restrict__ gcl,
    const unsigned* __restrict__ counts, float* __restrict__ out) {
  const int b = blockIdx.x;
  const int tid = threadIdx.x;
  const int lane = tid & 63;
  const int wave = tid >> 6;
  __shared__ float qs[1024];
  __shared__ unsigned skey[CAND_CAP];
  __shared__ int ci[CAND_CAP];
  __shared__ double sv[REF_CAP];
  __shared__ int rci[REF_CAP];
  __shared__ int s_cnt, s_rcnt;
  __shared__ unsigned s_tkey;
  __shared__ int topi[16];
  __shared__ double tops[16];
  __shared__ float wgt[16];
  if (tid == 0) { s_cnt = 0; s_rcnt = 0; }
  ((float4*)qs)[tid] = ((const float4*)(qc + (size_t)b * D_DIM))[tid];
  __syncthreads();
  {
    unsigned c = counts[(size_t)b * 256 + tid];
    if (c > CELL_CAP) c = CELL_CAP;
    const size_t base = ((size_t)b * 256 + tid) * CELL_CAP;
    for (unsigned p = 0; p < c; ++p) {
      const unsigned e = gcl[base + p];
      int pos = atomicAdd(&s_cnt, 1);
      if (pos < CAND_CAP) {
        skey[pos] = e >> 16;
        ci[pos] = (int)(e & 0xFFFFu);
      }
    }
  }
  __syncthreads();
  int cnt = s_cnt;
  if (cnt > CAND_CAP) cnt = CAND_CAP;
  // Wave 0: 16th-largest fp16 key -> refine threshold. Margin 8e-3 covers
  // ~10 sigma of i8-dot noise (sigma ~7.9e-4) + fp16 quantization.
  if (wave == 0) {
    unsigned wk[8];
#pragma unroll
    for (int j = 0; j < 8; ++j) {
      const int s = lane + j * 64;
      wk[j] = (s < cnt) ? skey[s] : 0u;
    }
    unsigned sk = 0;
    for (int it = 0; it < 16; ++it) {
      unsigned loc = 0;
#pragma unroll
      for (int j = 0; j < 8; ++j) loc = max(loc, wk[j]);
      unsigned mx = loc;
#pragma unroll
      for (int off = 32; off; off >>= 1)
        mx = max(mx, (unsigned)__shfl_xor((int)mx, off));
      unsigned long long msk = __ballot(loc == mx && mx != 0u);
      int winner = __ffsll(msk) - 1;
      if (lane == winner) {
#pragma unroll
        for (int j = 0; j < 8; ++j)
          if (wk[j] == mx) { wk[j] = 0u; break; }
      }
      if (mx != 0u) sk = mx;
    }
    if (lane == 0) {
      const float sf = __half2float(__ushort_as_half(key2h(sk)));
      const unsigned short tb = __half_as_ushort(__float2half(sf - 8e-3f));
      s_tkey = h2key((unsigned)tb);
    }
  }
  __syncthreads();
  const unsigned tkey = s_tkey;
  for (int i = tid; i < cnt; i += 256) {
    if (skey[i] >= tkey) {
      int pos = atomicAdd(&s_rcnt, 1);
      if (pos < REF_CAP) rci[pos] = ci[i];
    }
  }
  __syncthreads();
  int rcnt = s_rcnt;
  if (rcnt > REF_CAP) rcnt = REF_CAP;
  const double sq = (double)invq[b];
  for (int i = wave; i < rcnt; i += 4) {
    const float4* p4 = (const float4*)(pat + (size_t)rci[i] * D_DIM);
    const float4* q4 = (const float4*)qs;
    double acc = 0.0;
#pragma unroll
    for (int j = 0; j < 4; ++j) {
      float4 p = p4[lane + j * 64];
      float4 q = q4[lane + j * 64];
      acc += (double)p.x * q.x + (double)p.y * q.y + (double)p.z * q.z +
             (double)p.w * q.w;
    }
#pragma unroll
    for (int off = 32; off; off >>= 1) acc += __shfl_xor(acc, off);
    if (lane == 0) sv[i] = acc * sq * (double)invp[rci[i]];
  }
  __syncthreads();
  if (wave == 0) {
    for (int k = 0; k < 16; ++k) {
      double bs = -1e300;
      int bi = 0x7FFFFFFF, bslot = -1;
      for (int s = lane; s < rcnt; s += 64) {
        double d = sv[s];
        int id = rci[s];
        if (d > bs || (d == bs && id < bi)) { bs = d; bi = id; bslot = s; }
      }
#pragma unroll
      for (int off = 32; off; off >>= 1) {
        double ds = __shfl_xor(bs, off);
        int di = __shfl_xor(bi, off);
        int dsl = __shfl_xor(bslot, off);
        if (ds > bs || (ds == bs && di < bi)) { bs = ds; bi = di; bslot = dsl; }
      }
      if (lane == 0) {
        if (bi == 0x7FFFFFFF) bi = 0;  // safety: never index OOB
        topi[k] = bi;
        tops[k] = bs;
        if (bslot >= 0) sv[bslot] = -1e301;
      }
    }
    if (lane < 16) {
      float ts = (float)tops[lane];
      wgt[lane] = ts * (1.0f + comp[topi[lane]]);
    }
  }
  __syncthreads();
  if (tid == 0) {  // softmax over 16
    float m = wgt[0];
    for (int k = 1; k < 16; ++k) m = fmaxf(m, wgt[k]);
    float e[16];
    float ssum = 0.f;
    for (int k = 0; k < 16; ++k) {
      e[k] = expf(wgt[k] - m);
      ssum += e[k];
    }
    for (int k = 0; k < 16; ++k) wgt[k] = e[k] / ssum;
  }
  __syncthreads();
  float4 a4 = {0.f, 0.f, 0.f, 0.f};
  for (int k = 0; k < 16; ++k) {
    float4 pv = ((const float4*)(pat + (size_t)topi[k] * D_DIM))[tid];
    const float w = wgt[k];
    a4.x += w * pv.x;
    a4.y += w * pv.y;
    a4.z += w * pv.z;
    a4.w += w * pv.w;
  }
  ((float4*)(out + (size_t)b * D_DIM))[tid] = a4;
  if (tid == 0) out[1048576 + b] = (float)tops[0];
  if (tid < 16) {
    out[1048576 + 1024 + b * 16 + tid] = (float)topi[tid];
    out[1048576 + 1024 + 16384 + b * 16 + tid] = (float)tops[tid];
  }
}

extern "C" void kernel_launch(void* const* d_in, const int* in_sizes, int n_in,
                              void* d_out, int out_size, void* d_ws,
                              size_t ws_size, hipStream_t stream) {
  const float* qc = (const float*)d_in[0];
  const float* pat = (const float*)d_in[1];
  const float* comp = (const float*)d_in[2];
  char* ws = (char*)d_ws;
  unsigned char* pn8 = (unsigned char*)(ws + 0);              // 64 MB
  unsigned char* qn8 = (unsigned char*)(ws + 67108864);       // 1 MB
  unsigned* gcl = (unsigned*)(ws + 69206016);                 // 16 MB
  unsigned* counts = (unsigned*)(ws + 85983232);              // 1 MB
  float* invp = (float*)(ws + 88080384);                      // 256 KB
  float* invq = (float*)(ws + 88342528);                      // 4 KB
  float* out = (float*)d_out;

  k_rownorm<<<C_P / 4, 256, 0, stream>>>(pat, pn8, invp, C_P);
  k_rownorm<<<B_Q / 4, 256, 0, stream>>>(qc, qn8, invq, B_Q);
  dim3 g2(C_P / BN, B_Q / BM);
  k_gemm<<<g2, 512, 0, stream>>>(qn8, pn8, gcl, counts);
  k_final<<<B_Q, 256, 0, stream>>>(qc, pat, comp, invq, invp, gcl, counts, out);
}